// Round 3
// baseline (227.880 us; speedup 1.0000x reference)
//
#include <hip/hip_runtime.h>

// Nearest-neighbor gather resample.
// idx:    [B, 2, N] float32 (row, col) coords
// source: [B, 640, 640, 3] float32
// out:    [B, N, 3] float32; zero where rounded coord out of bounds.
//
// Semantics: coord = (int)(v + 0.5f)  (trunc toward zero) ==
// jnp.trunc(idx+0.5).astype(int32). Validity tested on UNCLAMPED coord.
//
// R2 change vs R1: gathers use device-scope (agent) relaxed atomic loads ->
// L1 bypass. Theory: random divergent gathers serialize on per-CU L1 MSHRs
// (~30 outstanding misses); agent-scope loads are served from L2 directly,
// whose per-channel miss tracking is much deeper. idx loads/stores stay on
// the normal (coalesced, streaming) path. XCD swizzle from R1 kept: per-XCD
// gather working set ~10 MB -> mostly L2 hits.

#define HS 640
#define WS 640
#define NC 3

template <bool SWIZ>
__global__ __launch_bounds__(256) void resample_nn_kernel(
    const float* __restrict__ idx,   // [B, 2, N]
    const float* __restrict__ src,   // [B, HS, WS, NC]
    float* __restrict__ out,         // [B, N, NC]
    int N,                           // pixels per batch (quad-divisible)
    int blocks_per_batch,            // (N/4)/256
    int batches_per_xcd)             // B/8
{
    int b, q0;
    if (SWIZ) {
        // consecutive blockIdx -> consecutive XCDs (round-robin dispatch)
        int xcd  = blockIdx.x & 7;
        int slot = blockIdx.x >> 3;                  // per-XCD block sequence
        b  = xcd * batches_per_xcd + slot / blocks_per_batch;
        int blk = slot % blocks_per_batch;
        q0 = blk * (int)blockDim.x + (int)threadIdx.x;
    } else {
        long long tid = (long long)blockIdx.x * blockDim.x + threadIdx.x;
        int quads_per_b = N >> 2;
        b  = (int)(tid / quads_per_b);
        q0 = (int)(tid % quads_per_b);
    }
    int n0 = q0 << 2;

    const float* idx_b = idx + (size_t)b * 2 * N;
    float4 r4 = *(const float4*)(idx_b + n0);        // coalesced
    float4 c4 = *(const float4*)(idx_b + N + n0);    // coalesced

    const float* src_b = src + (size_t)b * (HS * WS * NC);

    float rr[4] = {r4.x, r4.y, r4.z, r4.w};
    float cc[4] = {c4.x, c4.y, c4.z, c4.w};

    bool valid[4];
    const float* pp[4];
#pragma unroll
    for (int i = 0; i < 4; ++i) {
        int ir = (int)(rr[i] + 0.5f);                // trunc toward zero
        int ic = (int)(cc[i] + 0.5f);
        valid[i] = (ir >= 0) & (ic >= 0) & (ir < HS) & (ic < WS);
        int irc = min(max(ir, 0), HS - 1);
        int icc = min(max(ic, 0), WS - 1);
        pp[i] = src_b + ((size_t)irc * WS + icc) * NC;
    }

    // device-scope loads: bypass L1, overlap misses at L2 level.
    float g[12];
#pragma unroll
    for (int i = 0; i < 4; ++i) {
#pragma unroll
        for (int c = 0; c < NC; ++c) {
            g[3 * i + c] = __hip_atomic_load((const float*)(pp[i] + c),
                                             __ATOMIC_RELAXED,
                                             __HIP_MEMORY_SCOPE_AGENT);
        }
    }

    float v[12];
#pragma unroll
    for (int i = 0; i < 4; ++i) {
        v[3 * i + 0] = valid[i] ? g[3 * i + 0] : 0.0f;
        v[3 * i + 1] = valid[i] ? g[3 * i + 1] : 0.0f;
        v[3 * i + 2] = valid[i] ? g[3 * i + 2] : 0.0f;
    }

    float4* o = (float4*)(out + ((size_t)b * N + n0) * NC);
    o[0] = make_float4(v[0], v[1], v[2], v[3]);
    o[1] = make_float4(v[4], v[5], v[6], v[7]);
    o[2] = make_float4(v[8], v[9], v[10], v[11]);
}

extern "C" void kernel_launch(void* const* d_in, const int* in_sizes, int n_in,
                              void* d_out, int out_size, void* d_ws, size_t ws_size,
                              hipStream_t stream) {
    const float* idx = (const float*)d_in[0];
    const float* src = (const float*)d_in[1];
    float* out = (float*)d_out;

    int B = in_sizes[1] / (HS * WS * NC);        // 16
    int N = in_sizes[0] / (2 * B);               // 262144

    int block = 256;
    int quads_per_b = N >> 2;

    if ((B % 8 == 0) && (quads_per_b % block == 0)) {
        int blocks_per_batch = quads_per_b / block;       // 256
        int batches_per_xcd  = B / 8;                     // 2
        int grid = B * blocks_per_batch;                  // 4096
        resample_nn_kernel<true><<<grid, block, 0, stream>>>(
            idx, src, out, N, blocks_per_batch, batches_per_xcd);
    } else {
        long long total_quads = (long long)B * quads_per_b;
        int grid = (int)((total_quads + block - 1) / block);
        resample_nn_kernel<false><<<grid, block, 0, stream>>>(
            idx, src, out, N, 0, 0);
    }
}

// Round 4
// 190.021 us; speedup vs baseline: 1.1992x; 1.1992x over previous
//
#include <hip/hip_runtime.h>

// Nearest-neighbor gather resample.
// idx:    [B, 2, N] float32 (row, col) coords
// source: [B, 640, 640, 3] float32
// out:    [B, N, 3] float32; zero where rounded coord out of bounds.
//
// Semantics: coord = (int)(v + 0.5f)  (trunc toward zero) ==
// jnp.trunc(idx+0.5).astype(int32). Validity tested on UNCLAMPED coord.
//
// R3 change vs R1: 8 pixels/thread with all 8 dwordx3 gathers issued
// back-to-back before any consumption -> 2x per-wave memory-level
// parallelism. Discriminates latency-bound (helps ~2x) vs structural
// L1-miss-path throughput bound (neutral). XCD swizzle kept. R2's
// agent-scope bypass reverted (scalarized + still consumed MSHRs).

#define HS 640
#define WS 640
#define NC 3
#define PPT 8   // pixels per thread

struct alignas(4) F3 { float x, y, z; };

template <bool SWIZ>
__global__ __launch_bounds__(256) void resample_nn_kernel(
    const float* __restrict__ idx,   // [B, 2, N]
    const float* __restrict__ src,   // [B, HS, WS, NC]
    float* __restrict__ out,         // [B, N, NC]
    int N,                           // pixels per batch (divisible by 8*256)
    int blocks_per_batch,            // N/(PPT*256)
    int batches_per_xcd)             // B/8
{
    int b, p0;
    if (SWIZ) {
        // consecutive blockIdx -> consecutive XCDs (round-robin dispatch)
        int xcd  = blockIdx.x & 7;
        int slot = blockIdx.x >> 3;                  // per-XCD block sequence
        b  = xcd * batches_per_xcd + slot / blocks_per_batch;
        int blk = slot % blocks_per_batch;
        p0 = (blk * (int)blockDim.x + (int)threadIdx.x) * PPT;
    } else {
        long long tid = (long long)blockIdx.x * blockDim.x + threadIdx.x;
        long long pix = tid * PPT;
        b  = (int)(pix / N);
        p0 = (int)(pix % N);
    }

    const float* idx_b = idx + (size_t)b * 2 * N;
    // 8 row coords + 8 col coords: 2+2 float4 loads, contiguous per thread
    float4 r0 = *(const float4*)(idx_b + p0);
    float4 r1 = *(const float4*)(idx_b + p0 + 4);
    float4 c0 = *(const float4*)(idx_b + N + p0);
    float4 c1 = *(const float4*)(idx_b + N + p0 + 4);

    const float* src_b = src + (size_t)b * (HS * WS * NC);

    float rr[PPT] = {r0.x, r0.y, r0.z, r0.w, r1.x, r1.y, r1.z, r1.w};
    float cc[PPT] = {c0.x, c0.y, c0.z, c0.w, c1.x, c1.y, c1.z, c1.w};

    bool valid[PPT];
    const F3* pp[PPT];
#pragma unroll
    for (int i = 0; i < PPT; ++i) {
        int ir = (int)(rr[i] + 0.5f);                // trunc toward zero
        int ic = (int)(cc[i] + 0.5f);
        valid[i] = (ir >= 0) & (ic >= 0) & (ir < HS) & (ic < WS);
        int irc = min(max(ir, 0), HS - 1);
        int icc = min(max(ic, 0), WS - 1);
        pp[i] = (const F3*)(src_b + ((size_t)irc * WS + icc) * NC);
    }

    // issue all 8 gathers before consuming any -> 8 vmem ops in flight
    F3 g[PPT];
#pragma unroll
    for (int i = 0; i < PPT; ++i) g[i] = *pp[i];

    float v[PPT * NC];
#pragma unroll
    for (int i = 0; i < PPT; ++i) {
        v[3 * i + 0] = valid[i] ? g[i].x : 0.0f;
        v[3 * i + 1] = valid[i] ? g[i].y : 0.0f;
        v[3 * i + 2] = valid[i] ? g[i].z : 0.0f;
    }

    // 8 pixels * 12B = 96B contiguous per thread -> 6 float4 stores
    float4* o = (float4*)(out + ((size_t)b * N + p0) * NC);
#pragma unroll
    for (int j = 0; j < 6; ++j)
        o[j] = make_float4(v[4 * j], v[4 * j + 1], v[4 * j + 2], v[4 * j + 3]);
}

extern "C" void kernel_launch(void* const* d_in, const int* in_sizes, int n_in,
                              void* d_out, int out_size, void* d_ws, size_t ws_size,
                              hipStream_t stream) {
    const float* idx = (const float*)d_in[0];
    const float* src = (const float*)d_in[1];
    float* out = (float*)d_out;

    int B = in_sizes[1] / (HS * WS * NC);        // 16
    int N = in_sizes[0] / (2 * B);               // 262144

    int block = 256;
    int pix_per_block = block * PPT;             // 2048

    if ((B % 8 == 0) && (N % pix_per_block == 0)) {
        int blocks_per_batch = N / pix_per_block;         // 128
        int batches_per_xcd  = B / 8;                     // 2
        int grid = B * blocks_per_batch;                  // 2048
        resample_nn_kernel<true><<<grid, block, 0, stream>>>(
            idx, src, out, N, blocks_per_batch, batches_per_xcd);
    } else {
        long long total = (long long)B * N;
        int grid = (int)((total + (long long)pix_per_block - 1) / pix_per_block);
        resample_nn_kernel<false><<<grid, block, 0, stream>>>(
            idx, src, out, N, 0, 0);
    }
}